// Round 5
// baseline (1428.656 us; speedup 1.0000x reference)
//
#include <hip/hip_runtime.h>
#include <hip/hip_bf16.h>

using u16 = unsigned short;
using short8 = __attribute__((ext_vector_type(8))) short;
using floatx4 = __attribute__((ext_vector_type(4))) float;

#define DEVI static __device__ __forceinline__

constexpr int cB = 4, cN = 4096, cD = 768, cE = 4, cS = 1024, cH = 3072;
constexpr int cES = cE * cS; // 4096
constexpr int cHC = cH / 2;  // 1536 H-chunk

DEVI u16 f2bf(float f) {
  union { float f; unsigned u; } v; v.f = f;
  unsigned r = v.u + 0x7fffu + ((v.u >> 16) & 1u); // RNE
  return (u16)(r >> 16);
}
DEVI float bf2f(u16 b) {
  union { unsigned u; float f; } v; v.u = ((unsigned)b) << 16;
  return v.f;
}
DEVI float gelu_tanh(float x) {
  float z = 1.5957691216057308f * (x + 0.044715f * x * x * x);
  z = fminf(fmaxf(z, -30.f), 30.f);
  float e = __expf(z);
  float t = (e - 1.f) / (e + 1.f);
  return 0.5f * x * (1.f + t);
}

// async global->LDS, 16B per lane; lds dest = wave-uniform base + lane*16
DEVI void glds16(const u16* g, u16* l) {
  __builtin_amdgcn_global_load_lds(
      (const __attribute__((address_space(1))) void*)g,
      (__attribute__((address_space(3))) void*)l, 16, 0, 0);
}

// ---------------- zero fp32 buffer ----------------
__global__ __launch_bounds__(256) void zero_kernel(float* __restrict__ p, int n) {
  int i = blockIdx.x * 256 + threadIdx.x;
  if (i < n) p[i] = 0.f;
}

// ---------------- elementwise convert f32 -> bf16 ----------------
__global__ __launch_bounds__(256) void convert_kernel(const float* __restrict__ in,
                                                      u16* __restrict__ out, long n) {
  long stride = (long)gridDim.x * 256 * 4;
  for (long idx = ((long)blockIdx.x * 256 + threadIdx.x) * 4; idx < n; idx += stride) {
    float4 v = *(const float4*)(in + idx);
    ushort4 o;
    o.x = f2bf(v.x); o.y = f2bf(v.y); o.z = f2bf(v.z); o.w = f2bf(v.w);
    *(ushort4*)(out + idx) = o;
  }
}

// ---------------- batched transpose [R][C] -> [C][R], output bf16 ----------------
DEVI u16 to_bf(float f) { return f2bf(f); }
DEVI u16 to_bf(u16 u) { return u; }

template <typename Tin>
__global__ __launch_bounds__(256) void transpose_bf16_kernel(const Tin* __restrict__ in,
                                                             u16* __restrict__ out,
                                                             int R, int C,
                                                             long strideIn, long strideOut) {
  __shared__ u16 tile[64][65];
  const Tin* inb = in + (long)blockIdx.z * strideIn;
  u16* outb = out + (long)blockIdx.z * strideOut;
  const int r0 = blockIdx.y * 64, c0 = blockIdx.x * 64;
  const int tid = threadIdx.x;
#pragma unroll
  for (int i = 0; i < 16; i++) {
    int idx = i * 256 + tid;
    int r = idx >> 6, c = idx & 63;
    tile[r][c] = to_bf(inb[(long)(r0 + r) * C + (c0 + c)]);
  }
  __syncthreads();
#pragma unroll
  for (int i = 0; i < 16; i++) {
    int idx = i * 256 + tid;
    int r = idx >> 6, c = idx & 63;
    outb[(long)(c0 + r) * R + (r0 + c)] = tile[c][r];
  }
}

// ================= 128^2 engine (R1, kept for skinny grids) =================
template <int EPI>
__global__ __launch_bounds__(256, 2) void gemm_nt(const u16* __restrict__ A,
                                                  const u16* __restrict__ Bm,
                                                  void* __restrict__ Cout,
                                                  int M, int Nn, int K,
                                                  long ldA, long ldB, long ldC,
                                                  long strideA, long strideB, int modB,
                                                  long strideC,
                                                  const float* __restrict__ epiVec,
                                                  long epiStride, int epiMod) {
  __shared__ u16 lds[4 * 8192]; // 4 bufs x (A 4096 + B 4096) = 64KB

  const int gx = gridDim.x;
  const int nwg = gx * gridDim.y;
  int flat = blockIdx.y * gx + blockIdx.x;
  if ((nwg & 7) == 0) flat = (flat & 7) * (nwg >> 3) + (flat >> 3);
  const int bxs = flat % gx, bys = flat / gx;

  const int bz = blockIdx.z;
  const u16* Ab = A + (long)bz * strideA;
  const u16* Bb = Bm + (long)(bz % modB) * strideB;
  const float* ev = epiVec + (long)(bz % epiMod) * epiStride;
  const int tileM = bys * 128, tileN = bxs * 128;
  const int tid = threadIdx.x;
  const int wave = tid >> 6, lane = tid & 63;
  const int quad = lane >> 4, l16 = lane & 15;
  const int wm = (wave >> 1) * 64, wn = (wave & 1) * 64;

  const int swzk = (((lane & 3) ^ ((lane >> 3) & 3)) << 3);
  const int r0 = wave * 32 + (lane >> 2);
  const u16* aG0 = Ab + (long)(tileM + r0) * ldA + swzk;
  const u16* aG1 = Ab + (long)(tileM + r0 + 16) * ldA + swzk;
  const u16* bG0 = Bb + (long)(tileN + r0) * ldB + swzk;
  const u16* bG1 = Bb + (long)(tileN + r0 + 16) * ldB + swzk;
  const int ldsW = wave * 1024;

  const int NT = K >> 5;

  auto STAGE = [&](int tt) {
    u16* l = &lds[(tt & 3) * 8192];
    const long ko = (long)tt << 5;
    glds16(aG0 + ko, l + ldsW);
    glds16(aG1 + ko, l + ldsW + 512);
    glds16(bG0 + ko, l + 4096 + ldsW);
    glds16(bG1 + ko, l + 4096 + ldsW + 512);
  };

  floatx4 acc[4][4] = {};
  const int sread = ((quad ^ ((l16 >> 1) & 3)) << 3);

  STAGE(0);
  if (NT > 1) STAGE(1);
  if (NT > 2) STAGE(2);

  for (int t = 0; t < NT; t++) {
    asm volatile("s_barrier" ::: "memory");
    if (t + 3 < NT) STAGE(t + 3);
    const int ahead = NT - 1 - t;
    if (ahead >= 3)      asm volatile("s_waitcnt vmcnt(12)" ::: "memory");
    else if (ahead == 2) asm volatile("s_waitcnt vmcnt(8)" ::: "memory");
    else if (ahead == 1) asm volatile("s_waitcnt vmcnt(4)" ::: "memory");
    else                 asm volatile("s_waitcnt vmcnt(0)" ::: "memory");
    asm volatile("s_barrier" ::: "memory");

    const u16* As = &lds[(t & 3) * 8192];
    const u16* Bs = As + 4096;
    short8 af[4], bq[4];
#pragma unroll
    for (int i = 0; i < 4; i++)
      af[i] = *(const short8*)&As[(wm + i * 16 + l16) * 32 + sread];
#pragma unroll
    for (int j = 0; j < 4; j++)
      bq[j] = *(const short8*)&Bs[(wn + j * 16 + l16) * 32 + sread];
    __builtin_amdgcn_s_setprio(1);
#pragma unroll
    for (int i = 0; i < 4; i++)
#pragma unroll
      for (int j = 0; j < 4; j++)
        acc[i][j] = __builtin_amdgcn_mfma_f32_16x16x32_bf16(af[i], bq[j], acc[i][j], 0, 0, 0);
    __builtin_amdgcn_s_setprio(0);
  }

  const long cBase = (long)bz * strideC;
#pragma unroll
  for (int i = 0; i < 4; i++) {
#pragma unroll
    for (int r = 0; r < 4; r++) {
      const int row = tileM + wm + i * 16 + quad * 4 + r;
      float rscale = 1.f;
      if (EPI == 1 || EPI == 4) rscale = 1.f / ev[row];
#pragma unroll
      for (int j = 0; j < 4; j++) {
        const int col = tileN + wn + j * 16 + l16;
        float v = acc[i][j][r];
        const long cIdx = cBase + (long)row * ldC + col;
        if (EPI == 0) v = __expf(v);
        if (EPI == 1 || EPI == 4) v *= rscale;
        if (EPI == 2) v = gelu_tanh(v + ev[col]);
        if (EPI == 3) v = v + ev[col];
        if (EPI == 5) v = v + bf2f(((u16*)Cout)[cIdx]);
        if (EPI == 4)
          ((float*)Cout)[cIdx] = v;
        else
          ((u16*)Cout)[cIdx] = f2bf(v);
      }
    }
  }
}

// ================= 256^2 engine, reg-prefetch pipeline (derived waits) =========
// 4 phases per K-tile(64); ds_reads issued ONE PHASE AHEAD into alternating
// reg sets (X/Y); counted lgkmcnt (in-order DS completion) => MFMA burst
// overlaps next phase's LDS drain. One s_barrier per phase. vmcnt(4) at ph2-end
// (before the barrier) makes T(kt+1) collectively resident for ph3's next-tile
// read prefetch. Stage ledger identical to R3 (verified passing).
// EPI 6: exp->bf16 + fused col/row sums.
template <int EPI>
__global__ __launch_bounds__(512, 2) void gemm256(const u16* __restrict__ A,
                                                  const u16* __restrict__ Bm,
                                                  void* __restrict__ Cout,
                                                  int M, int Nn, int K,
                                                  long ldA, long ldB, long ldC,
                                                  long strideA, long strideB, int modB,
                                                  long strideC,
                                                  const float* __restrict__ epiVec,
                                                  long epiStride, int epiMod,
                                                  float* __restrict__ Zc,
                                                  float* __restrict__ Zr) {
  __shared__ u16 lds[2][2][2][8192]; // [buf][A=0/B=1][kh][256 rows * 32 k]

  // bijective XCD swizzle (m204 form; works for any nwg)
  const int gx = gridDim.x;
  const int nwg = gx * gridDim.y;
  int flat = blockIdx.y * gx + blockIdx.x;
  {
    const int q = nwg >> 3, r = nwg & 7, xc = flat & 7, o = flat >> 3;
    flat = (xc < r ? xc * (q + 1) : r * (q + 1) + (xc - r) * q) + o;
  }
  const int bxs = flat % gx, bys = flat / gx;

  const int bz = blockIdx.z;
  const u16* __restrict__ Ab = A + (long)bz * strideA;
  const u16* __restrict__ Bb = Bm + (long)(bz % modB) * strideB;
  const float* __restrict__ ev = epiVec + (long)(bz % epiMod) * epiStride;
  const int tileM = bys * 256, tileN = bxs * 256;
  const int tid = threadIdx.x;
  const int wave = tid >> 6, lane = tid & 63;
  const int quad = lane >> 4, l16 = lane & 15;
  const int wr = wave >> 2, wc = wave & 3;

  const int kswz = (((lane & 3) ^ ((lane >> 3) & 3)) << 3);
  const int srow = wave * 32 + (lane >> 2);
  const u16* gA = Ab + (long)(tileM + srow) * ldA + kswz;
  const u16* gB = Bb + (long)(tileN + srow) * ldB + kswz;

  const int rdsw = ((quad ^ ((l16 >> 1) & 3)) << 3);
  const int aOff = (wr * 128 + l16) * 32 + rdsw; // + m*512
  const int bOff = (wc * 64 + l16) * 32 + rdsw;  // + n*512

  const int NT = K >> 6; // K multiple of 64; NT even >= 4 at all call sites

#define STA256(buf, kh, tt) do {                                   \
    const u16* _g = gA + ((long)(tt) << 6) + ((kh) << 5);          \
    u16* _l = &lds[buf][0][kh][wave * 1024];                       \
    glds16(_g, _l); glds16(_g + 16 * ldA, _l + 512); } while (0)
#define STB256(buf, kh, tt) do {                                   \
    const u16* _g = gB + ((long)(tt) << 6) + ((kh) << 5);          \
    u16* _l = &lds[buf][1][kh][wave * 1024];                       \
    glds16(_g, _l); glds16(_g + 16 * ldB, _l + 512); } while (0)
#define BAR256 asm volatile("s_barrier" ::: "memory")
#define LGKM(n) asm volatile("s_waitcnt lgkmcnt(" #n ")" ::: "memory")

  floatx4 acc[8][4] = {};
  short8 afX[4], afY[4], bqX[4], bqY[4];

#define MFMA16(afS, bqS, mb)                                                        \
    __builtin_amdgcn_s_setprio(1);                                                  \
    _Pragma("unroll") for (int i = 0; i < 4; i++)                                    \
      _Pragma("unroll") for (int n = 0; n < 4; n++)                                  \
        acc[(mb) + i][n] =                                                           \
            __builtin_amdgcn_mfma_f32_16x16x32_bf16(afS[i], bqS[n], acc[(mb)+i][n], 0, 0, 0); \
    __builtin_amdgcn_s_setprio(0)

  // ---- prologue: stage T0 (4 halves) + T1 (3 halves; 4th staged at kt0.ph0)
  STA256(0, 0, 0); STB256(0, 0, 0); STA256(0, 1, 0); STB256(0, 1, 0);
  STB256(1, 0, 1); STA256(1, 0, 1); STB256(1, 1, 1);
  asm volatile("s_waitcnt vmcnt(6)" ::: "memory"); // T0 resident (per-wave)
  BAR256;                                          // collective
  // preload g0(T0): A m0-3 ks0 -> afX, B ks0 -> bqX
#pragma unroll
  for (int i = 0; i < 4; i++) afX[i] = *(const short8*)&lds[0][0][0][aOff + i * 512];
#pragma unroll
  for (int n = 0; n < 4; n++) bqX[n] = *(const short8*)&lds[0][1][0][bOff + n * 512];

  // Per tile kt (buf c), reg-prefetch schedule (reads are for NEXT group):
  //  ph0: R{afY<-A m4-7 ks0}        STA(c^1,kh1,kt+1)  lgkm(4)  M(afX,bqX,0)         BAR
  //  ph1: R{afX<-A m0-3 ks1, bqY}   STB(c,kh0,kt+2)    lgkm(8)  M(afY,bqX,4)         BAR
  //  ph2: R{afY<-A m4-7 ks1}        STA(c,kh0,kt+2)    lgkm(4)  M(afX,bqY,0)  VM     BAR
  //  ph3: R{afX,bqX <- g0(kt+1)}    STB(c,kh1,kt+2)    lgkm(8)  M(afY,bqY,4)         BAR
  // VM at ph2 = vmcnt(4) (T(kt+2) B.kh0+A.kh0 in flight) -> T(kt+1) resident;
  // the ph2 barrier makes it collective before ph3's next-tile reads.
#define TILE256(kt, buf) do {                                                        \
    const bool s1 = (kt) + 1 < NT, s2 = (kt) + 2 < NT;                               \
    /* ph0 */                                                                        \
    _Pragma("unroll") for (int i = 0; i < 4; i++)                                    \
      afY[i] = *(const short8*)&lds[buf][0][0][aOff + (4 + i) * 512];                \
    if (s1) STA256((buf) ^ 1, 1, (kt) + 1);                                          \
    LGKM(4);                                                                         \
    MFMA16(afX, bqX, 0);                                                             \
    BAR256;                                                                          \
    /* ph1 */                                                                        \
    _Pragma("unroll") for (int i = 0; i < 4; i++)                                    \
      afX[i] = *(const short8*)&lds[buf][0][1][aOff + i * 512];                      \
    _Pragma("unroll") for (int n = 0; n < 4; n++)                                    \
      bqY[n] = *(const short8*)&lds[buf][1][1][bOff + n * 512];                      \
    if (s2) STB256(buf, 0, (kt) + 2);                                                \
    LGKM(8);                                                                         \
    MFMA16(afY, bqX, 4);                                                             \
    BAR256;                                                                          \
    /* ph2 */                                                                        \
    _Pragma("unroll") for (int i = 0; i < 4; i++)                                    \
      afY[i] = *(const short8*)&lds[buf][0][1][aOff + (4 + i) * 512];                \
    if (s2) STA256(buf, 0, (kt) + 2);                                                \
    LGKM(4);                                                                         \
    MFMA16(afX, bqY, 0);                                                             \
    if (s2) asm volatile("s_waitcnt vmcnt(4)" ::: "memory");                         \
    else    asm volatile("s_waitcnt vmcnt(0)" ::: "memory");                         \
    BAR256;                                                                          \
    /* ph3 */                                                                        \
    if (s1) {                                                                        \
      _Pragma("unroll") for (int i = 0; i < 4; i++)                                  \
        afX[i] = *(const short8*)&lds[(buf) ^ 1][0][0][aOff + i * 512];              \
      _Pragma("unroll") for (int n = 0; n < 4; n++)                                  \
        bqX[n] = *(const short8*)&lds[(buf) ^ 1][1][0][bOff + n * 512];              \
    }                                                                                \
    if (s2) STB256(buf, 1, (kt) + 2);                                                \
    if (s1) { LGKM(8); } else { LGKM(0); }                                           \
    MFMA16(afY, bqY, 4);                                                             \
    BAR256;                                                                          \
  } while (0)

  for (int kt = 0; kt < NT; kt += 2) {
    TILE256(kt, 0);
    TILE256(kt + 1, 1);
  }
#undef TILE256
#undef MFMA16
#undef STA256
#undef STB256
#undef BAR256
#undef LGKM

  const long cBase = (long)bz * strideC;
  if (EPI == 6) {
    // exp + store + fused row/col sums. Zc/Zr pre-zeroed; atomic accumulate.
    float csum[4] = {0.f, 0.f, 0.f, 0.f};
#pragma unroll
    for (int m = 0; m < 8; m++) {
#pragma unroll
      for (int r = 0; r < 4; r++) {
        const int row = tileM + wr * 128 + m * 16 + quad * 4 + r;
        float rs = 0.f;
#pragma unroll
        for (int n = 0; n < 4; n++) {
          const int col = tileN + wc * 64 + n * 16 + l16;
          float v = __expf(acc[m][n][r]);
          ((u16*)Cout)[cBase + (long)row * ldC + col] = f2bf(v);
          rs += v;
          csum[n] += v;
        }
        rs += __shfl_xor(rs, 1, 64);
        rs += __shfl_xor(rs, 2, 64);
        rs += __shfl_xor(rs, 4, 64);
        rs += __shfl_xor(rs, 8, 64);
        if (l16 == 0) atomicAdd(&Zr[row], rs);
      }
    }
#pragma unroll
    for (int n = 0; n < 4; n++) {
      float c = csum[n];
      c += __shfl_xor(c, 16, 64);
      c += __shfl_xor(c, 32, 64);
      if (quad == 0) atomicAdd(&Zc[tileN + wc * 64 + n * 16 + l16], c);
    }
  } else {
#pragma unroll
    for (int m = 0; m < 8; m++) {
#pragma unroll
      for (int r = 0; r < 4; r++) {
        const int row = tileM + wr * 128 + m * 16 + quad * 4 + r;
        float rscale = 1.f;
        if (EPI == 1 || EPI == 4) rscale = 1.f / ev[row];
#pragma unroll
        for (int n = 0; n < 4; n++) {
          const int col = tileN + wc * 64 + n * 16 + l16;
          float v = acc[m][n][r];
          const long cIdx = cBase + (long)row * ldC + col;
          if (EPI == 0) v = __expf(v);
          if (EPI == 1 || EPI == 4) v *= rscale;
          if (EPI == 2) v = gelu_tanh(v + ev[col]);
          if (EPI == 3) v = v + ev[col];
          if (EPI == 5) v = v + bf2f(((u16*)Cout)[cIdx]);
          if (EPI == 4)
            ((float*)Cout)[cIdx] = v;
          else
            ((u16*)Cout)[cIdx] = f2bf(v);
        }
      }
    }
  }
}

extern "C" void kernel_launch(void* const* d_in, const int* in_sizes, int n_in,
                              void* d_out, int out_size, void* d_ws, size_t ws_size,
                              hipStream_t stream) {
  const float* x   = (const float*)d_in[0]; // [B,N,D]
  const float* phi = (const float*)d_in[1]; // [E,S,D]
  const float* w1  = (const float*)d_in[2]; // [E,D,H]
  const float* b1  = (const float*)d_in[3]; // [E,H]
  const float* w2  = (const float*)d_in[4]; // [E,H,D]
  const float* b2  = (const float*)d_in[5]; // [E,D]
  (void)in_sizes; (void)n_in; (void)out_size;
  float* out_f = (float*)d_out;

  char* ws = (char*)d_ws;
  size_t off = 0;
  auto carve = [&](size_t bytes) -> char* {
    char* p = ws + off;
    off += (bytes + 255) & ~(size_t)255;
    return p;
  };

  const size_t SZ_P  = (size_t)cN * cES * 2;            // 32 MiB (one P batch)
  const size_t SZ_HC = (size_t)cB * cE * cS * cHC * 2;  // 48 MiB (H chunk)

  // Mode A (cacheP): keep all 4 P batches -> phase C skips the exp-GEMM recompute.
  const bool cacheP = ws_size >= (size_t)306 * 1024 * 1024;

  u16 *Pall = nullptr, *PtA = nullptr, *HcA = nullptr;              // mode A
  u16 *Pb = nullptr, *Ptb = nullptr, *HcB = nullptr, *P2 = nullptr; // mode B
  if (cacheP) {
    Pall = (u16*)carve(4 * SZ_P);
    char* RPH = carve(SZ_HC);
    PtA = (u16*)RPH; HcA = (u16*)RPH;
  } else {
    char* R1 = carve(2 * SZ_P);
    Pb = (u16*)R1; Ptb = (u16*)(R1 + SZ_P); HcB = (u16*)R1; P2 = (u16*)R1;
  }
  u16* Xbf = (u16*)carve((size_t)cB * cN * cD * 2);
  char* R3r = carve((size_t)cB * cD * cN * 2);
  u16* Xt = (u16*)R3r;
  u16* Yv = (u16*)R3r;
  char* R4r = carve((size_t)cB * cES * cD * 2);
  u16* Slots = (u16*)R4r;
  u16* Yt    = (u16*)R4r;
  u16* Phibf = (u16*)carve((size_t)cES * cD * 2);
  u16* W1t = (u16*)carve((size_t)cE * cH * cD * 2);   // [e][h][d]
  u16* W2t = (u16*)carve((size_t)cE * cD * cH * 2);   // [e][d][h]
  float* Z1 = (float*)carve((size_t)(cB * cES + cB * cN) * 4);
  float* Z2 = Z1 + (size_t)cB * cES;

  // ---- phase 0: casts / weight transposes / zero sums ----
  convert_kernel<<<2048, 256, 0, stream>>>(x, Xbf, (long)cB * cN * cD);
  convert_kernel<<<1024, 256, 0, stream>>>(phi, Phibf, (long)cES * cD);
  transpose_bf16_kernel<float><<<dim3(cH / 64, cD / 64, cE), 256, 0, stream>>>(
      w1, W1t, cD, cH, (long)cD * cH, (long)cH * cD);
  transpose_bf16_kernel<float><<<dim3(cD / 64, cH / 64, cE), 256, 0, stream>>>(
      w2, W2t, cH, cD, (long)cH * cD, (long)cD * cH);
  transpose_bf16_kernel<float><<<dim3(cD / 64, cN / 64, cB), 256, 0, stream>>>(
      x, Xt, cN, cD, (long)cN * cD, (long)cD * cN);
  zero_kernel<<<(cB * (cES + cN)) / 256, 256, 0, stream>>>(Z1, cB * (cES + cN));

  // ---- phase A: per batch, P_b (exp + fused Z1/Z2 sums) -> Pt_b -> Slots_b ----
  for (int b = 0; b < cB; b++) {
    const u16* Xb = Xbf + (long)b * cN * cD;
    u16* Pdst = cacheP ? Pall + (size_t)b * cN * cES : Pb;
    u16* Ptmp = cacheP ? PtA : Ptb;
    gemm256<6><<<dim3(cES / 256, cN / 256, 1), 512, 0, stream>>>(
        Xb, Phibf, Pdst, cN, cES, cD, cD, cD, cES,
        0L, 0L, 1, 0L, Z1, 0, 1,
        Z1 + (long)b * cES, Z2 + (long)b * cN);
    transpose_bf16_kernel<u16><<<dim3(cES / 64, cN / 64, 1), 256, 0, stream>>>(
        Pdst, Ptmp, cN, cES, 0L, 0L);
    gemm_nt<1><<<dim3(cD / 128, cES / 128, 1), 256, 0, stream>>>(
        Ptmp, Xt + (long)b * cD * cN, Slots + (long)b * cES * cD,
        cES, cD, cN, cN, cN, cD,
        0L, 0L, 1, 0L, Z1 + (long)b * cES, 0, 1);
  }

  // ---- phase B: MLP in 2 H-chunks (bz = b*4+e), 256^2 engine ----
  u16* Hc = cacheP ? HcA : HcB;
  for (int hc = 0; hc < 2; hc++) {
    const int h0 = hc * cHC;
    gemm256<2><<<dim3(cHC / 256, cS / 256, cB * cE), 512, 0, stream>>>(
        Slots, W1t + (long)h0 * cD, Hc, cS, cHC, cD, cD, cD, cHC,
        (long)cS * cD, (long)cH * cD, cE, (long)cS * cHC, b1 + h0, cH, cE,
        nullptr, nullptr);
    if (hc == 0)
      gemm256<3><<<dim3(cD / 256, cS / 256, cB * cE), 512, 0, stream>>>(
          Hc, W2t + h0, Yv, cS, cD, cHC, cHC, cH, cD,
          (long)cS * cHC, (long)cD * cH, cE, (long)cS * cD, b2, cD, cE,
          nullptr, nullptr);
    else
      gemm256<5><<<dim3(cD / 256, cS / 256, cB * cE), 512, 0, stream>>>(
          Hc, W2t + h0, Yv, cS, cD, cHC, cHC, cH, cD,
          (long)cS * cHC, (long)cD * cH, cE, (long)cS * cD, b2, cD, cE,
          nullptr, nullptr);
  }

  // ---- phase C: Yt (into dead Slots region); combine (P recompute only if !cacheP) ----
  transpose_bf16_kernel<u16><<<dim3(cD / 64, cES / 64, cB), 256, 0, stream>>>(
      Yv, Yt, cES, cD, (long)cES * cD, (long)cD * cES);
  for (int bp = 0; bp < 2; bp++) {
    const u16* Psrc;
    if (cacheP) {
      Psrc = Pall + (size_t)(bp * 2) * cN * cES;
    } else {
      const u16* Xb = Xbf + (long)(bp * 2) * cN * cD;
      gemm256<0><<<dim3(cES / 256, cN / 256, 2), 512, 0, stream>>>(
          Xb, Phibf, P2, cN, cES, cD, cD, cD, cES,
          (long)cN * cD, 0L, 1, (long)cN * cES, Z1, 0, 1, nullptr, nullptr);
      Psrc = P2;
    }
    gemm_nt<4><<<dim3(cD / 128, cN / 128, 2), 256, 0, stream>>>(
        Psrc, Yt + (long)(bp * 2) * cD * cES, out_f + (long)(bp * 2) * cN * cD,
        cN, cD, cES, cES, cES, cD,
        (long)cN * cES, (long)cD * cES, 2, (long)cN * cD,
        Z2 + (long)(bp * 2) * cN, cN, 2);
  }
}

// Round 6
// 1059.041 us; speedup vs baseline: 1.3490x; 1.3490x over previous
//
#include <hip/hip_runtime.h>
#include <hip/hip_bf16.h>

using u16 = unsigned short;
using short8 = __attribute__((ext_vector_type(8))) short;
using floatx4 = __attribute__((ext_vector_type(4))) float;

#define DEVI static __device__ __forceinline__

constexpr int cB = 4, cN = 4096, cD = 768, cE = 4, cS = 1024, cH = 3072;
constexpr int cES = cE * cS; // 4096

DEVI u16 f2bf(float f) {
  union { float f; unsigned u; } v; v.f = f;
  unsigned r = v.u + 0x7fffu + ((v.u >> 16) & 1u); // RNE
  return (u16)(r >> 16);
}
DEVI float bf2f(u16 b) {
  union { unsigned u; float f; } v; v.u = ((unsigned)b) << 16;
  return v.f;
}
DEVI float gelu_tanh(float x) {
  float z = 1.5957691216057308f * (x + 0.044715f * x * x * x);
  z = fminf(fmaxf(z, -30.f), 30.f);
  float e = __expf(z);
  float t = (e - 1.f) / (e + 1.f);
  return 0.5f * x * (1.f + t);
}

// async global->LDS, 16B per lane; lds dest = wave-uniform base + lane*16
DEVI void glds16(const u16* g, u16* l) {
  __builtin_amdgcn_global_load_lds(
      (const __attribute__((address_space(1))) void*)g,
      (__attribute__((address_space(3))) void*)l, 16, 0, 0);
}

// ---------------- zero fp32 buffer ----------------
__global__ __launch_bounds__(256) void zero_kernel(float* __restrict__ p, int n) {
  int i = blockIdx.x * 256 + threadIdx.x;
  if (i < n) p[i] = 0.f;
}

// ---------------- elementwise convert f32 -> bf16 ----------------
__global__ __launch_bounds__(256) void convert_kernel(const float* __restrict__ in,
                                                      u16* __restrict__ out, long n) {
  long stride = (long)gridDim.x * 256 * 4;
  for (long idx = ((long)blockIdx.x * 256 + threadIdx.x) * 4; idx < n; idx += stride) {
    float4 v = *(const float4*)(in + idx);
    ushort4 o;
    o.x = f2bf(v.x); o.y = f2bf(v.y); o.z = f2bf(v.z); o.w = f2bf(v.w);
    *(ushort4*)(out + idx) = o;
  }
}

// ---------------- batched transpose [R][C] -> [C][R], output bf16 ----------------
// Vectorized (G13): float4/ushort4 loads, packed ushort4 stores. LDS pad 66
// -> writes conflict-free, reads ~2-way (free per m136).
template <typename Tin>
__global__ __launch_bounds__(256) void transpose_bf16_kernel(const Tin* __restrict__ in,
                                                             u16* __restrict__ out,
                                                             int R, int C,
                                                             long strideIn, long strideOut) {
  __shared__ u16 tile[64][66];
  const Tin* inb = in + (long)blockIdx.z * strideIn;
  u16* outb = out + (long)blockIdx.z * strideOut;
  const int r0 = blockIdx.y * 64, c0 = blockIdx.x * 64;
  const int tid = threadIdx.x;
#pragma unroll
  for (int i = 0; i < 4; i++) {
    int v = i * 256 + tid;
    int r = v >> 4, c4 = (v & 15) * 4;
    if constexpr (sizeof(Tin) == 4) {
      float4 f = *(const float4*)&inb[(long)(r0 + r) * C + (c0 + c4)];
      tile[r][c4 + 0] = f2bf(f.x); tile[r][c4 + 1] = f2bf(f.y);
      tile[r][c4 + 2] = f2bf(f.z); tile[r][c4 + 3] = f2bf(f.w);
    } else {
      ushort4 u = *(const ushort4*)&inb[(long)(r0 + r) * C + (c0 + c4)];
      tile[r][c4 + 0] = u.x; tile[r][c4 + 1] = u.y;
      tile[r][c4 + 2] = u.z; tile[r][c4 + 3] = u.w;
    }
  }
  __syncthreads();
#pragma unroll
  for (int i = 0; i < 4; i++) {
    int w = i * 256 + tid;
    int orow = w >> 4, oc4 = (w & 15) * 4;
    ushort4 u;
    u.x = tile[oc4 + 0][orow]; u.y = tile[oc4 + 1][orow];
    u.z = tile[oc4 + 2][orow]; u.w = tile[oc4 + 3][orow];
    *(ushort4*)&outb[(long)(c0 + orow) * R + (r0 + oc4)] = u;
  }
}

// ================= 128^2 engine (R1, kept for skinny grids) =================
template <int EPI>
__global__ __launch_bounds__(256, 2) void gemm_nt(const u16* __restrict__ A,
                                                  const u16* __restrict__ Bm,
                                                  void* __restrict__ Cout,
                                                  int M, int Nn, int K,
                                                  long ldA, long ldB, long ldC,
                                                  long strideA, long strideB, int modB,
                                                  long strideC,
                                                  const float* __restrict__ epiVec,
                                                  long epiStride, int epiMod) {
  __shared__ u16 lds[4 * 8192]; // 4 bufs x (A 4096 + B 4096) = 64KB

  const int gx = gridDim.x;
  const int nwg = gx * gridDim.y;
  int flat = blockIdx.y * gx + blockIdx.x;
  if ((nwg & 7) == 0) flat = (flat & 7) * (nwg >> 3) + (flat >> 3);
  const int bxs = flat % gx, bys = flat / gx;

  const int bz = blockIdx.z;
  const u16* Ab = A + (long)bz * strideA;
  const u16* Bb = Bm + (long)(bz % modB) * strideB;
  const float* ev = epiVec + (long)(bz % epiMod) * epiStride;
  const int tileM = bys * 128, tileN = bxs * 128;
  const int tid = threadIdx.x;
  const int wave = tid >> 6, lane = tid & 63;
  const int quad = lane >> 4, l16 = lane & 15;
  const int wm = (wave >> 1) * 64, wn = (wave & 1) * 64;

  const int swzk = (((lane & 3) ^ ((lane >> 3) & 3)) << 3);
  const int r0 = wave * 32 + (lane >> 2);
  const u16* aG0 = Ab + (long)(tileM + r0) * ldA + swzk;
  const u16* aG1 = Ab + (long)(tileM + r0 + 16) * ldA + swzk;
  const u16* bG0 = Bb + (long)(tileN + r0) * ldB + swzk;
  const u16* bG1 = Bb + (long)(tileN + r0 + 16) * ldB + swzk;
  const int ldsW = wave * 1024;

  const int NT = K >> 5;

  auto STAGE = [&](int tt) {
    u16* l = &lds[(tt & 3) * 8192];
    const long ko = (long)tt << 5;
    glds16(aG0 + ko, l + ldsW);
    glds16(aG1 + ko, l + ldsW + 512);
    glds16(bG0 + ko, l + 4096 + ldsW);
    glds16(bG1 + ko, l + 4096 + ldsW + 512);
  };

  floatx4 acc[4][4] = {};
  const int sread = ((quad ^ ((l16 >> 1) & 3)) << 3);

  STAGE(0);
  if (NT > 1) STAGE(1);
  if (NT > 2) STAGE(2);

  for (int t = 0; t < NT; t++) {
    asm volatile("s_barrier" ::: "memory");
    if (t + 3 < NT) STAGE(t + 3);
    const int ahead = NT - 1 - t;
    if (ahead >= 3)      asm volatile("s_waitcnt vmcnt(12)" ::: "memory");
    else if (ahead == 2) asm volatile("s_waitcnt vmcnt(8)" ::: "memory");
    else if (ahead == 1) asm volatile("s_waitcnt vmcnt(4)" ::: "memory");
    else                 asm volatile("s_waitcnt vmcnt(0)" ::: "memory");
    asm volatile("s_barrier" ::: "memory");

    const u16* As = &lds[(t & 3) * 8192];
    const u16* Bs = As + 4096;
    short8 af[4], bq[4];
#pragma unroll
    for (int i = 0; i < 4; i++)
      af[i] = *(const short8*)&As[(wm + i * 16 + l16) * 32 + sread];
#pragma unroll
    for (int j = 0; j < 4; j++)
      bq[j] = *(const short8*)&Bs[(wn + j * 16 + l16) * 32 + sread];
    __builtin_amdgcn_s_setprio(1);
#pragma unroll
    for (int i = 0; i < 4; i++)
#pragma unroll
      for (int j = 0; j < 4; j++)
        acc[i][j] = __builtin_amdgcn_mfma_f32_16x16x32_bf16(af[i], bq[j], acc[i][j], 0, 0, 0);
    __builtin_amdgcn_s_setprio(0);
  }

  const long cBase = (long)bz * strideC;
#pragma unroll
  for (int i = 0; i < 4; i++) {
#pragma unroll
    for (int r = 0; r < 4; r++) {
      const int row = tileM + wm + i * 16 + quad * 4 + r;
      float rscale = 1.f;
      if (EPI == 1 || EPI == 4) rscale = 1.f / ev[row];
#pragma unroll
      for (int j = 0; j < 4; j++) {
        const int col = tileN + wn + j * 16 + l16;
        float v = acc[i][j][r];
        const long cIdx = cBase + (long)row * ldC + col;
        if (EPI == 0) v = __expf(v);
        if (EPI == 1 || EPI == 4) v *= rscale;
        if (EPI == 2) v = gelu_tanh(v + ev[col]);
        if (EPI == 3) v = v + ev[col];
        if (EPI == 5) v = v + bf2f(((u16*)Cout)[cIdx]);
        if (EPI == 4)
          ((float*)Cout)[cIdx] = v;
        else
          ((u16*)Cout)[cIdx] = f2bf(v);
      }
    }
  }
}

// ================= 256^2 8-phase engine (R3/R4-verified K-loop, reverted) ======
// EPI 6: exp->bf16 + fused col/row sums.
template <int EPI>
__global__ __launch_bounds__(512, 2) void gemm256(const u16* __restrict__ A,
                                                  const u16* __restrict__ Bm,
                                                  void* __restrict__ Cout,
                                                  int M, int Nn, int K,
                                                  long ldA, long ldB, long ldC,
                                                  long strideA, long strideB, int modB,
                                                  long strideC,
                                                  const float* __restrict__ epiVec,
                                                  long epiStride, int epiMod,
                                                  float* __restrict__ Zc,
                                                  float* __restrict__ Zr) {
  __shared__ u16 lds[2][2][2][8192]; // [buf][A=0/B=1][kh][256 rows * 32 k]

  const int gx = gridDim.x;
  const int nwg = gx * gridDim.y;
  int flat = blockIdx.y * gx + blockIdx.x;
  {
    const int q = nwg >> 3, r = nwg & 7, xc = flat & 7, o = flat >> 3;
    flat = (xc < r ? xc * (q + 1) : r * (q + 1) + (xc - r) * q) + o;
  }
  const int bxs = flat % gx, bys = flat / gx;

  const int bz = blockIdx.z;
  const u16* __restrict__ Ab = A + (long)bz * strideA;
  const u16* __restrict__ Bb = Bm + (long)(bz % modB) * strideB;
  const float* __restrict__ ev = epiVec + (long)(bz % epiMod) * epiStride;
  const int tileM = bys * 256, tileN = bxs * 256;
  const int tid = threadIdx.x;
  const int wave = tid >> 6, lane = tid & 63;
  const int quad = lane >> 4, l16 = lane & 15;
  const int wr = wave >> 2, wc = wave & 3;

  const int kswz = (((lane & 3) ^ ((lane >> 3) & 3)) << 3);
  const int srow = wave * 32 + (lane >> 2);
  const u16* gA = Ab + (long)(tileM + srow) * ldA + kswz;
  const u16* gB = Bb + (long)(tileN + srow) * ldB + kswz;

  const int rdsw = ((quad ^ ((l16 >> 1) & 3)) << 3);
  const int aOff = (wr * 128 + l16) * 32 + rdsw; // + m*512
  const int bOff = (wc * 64 + l16) * 32 + rdsw;  // + n*512

  const int NT = K >> 6; // K multiple of 64, NT even >= 4 for all call sites

#define STA256(buf, kh, tt) do {                                   \
    const u16* _g = gA + ((long)(tt) << 6) + ((kh) << 5);          \
    u16* _l = &lds[buf][0][kh][wave * 1024];                       \
    glds16(_g, _l); glds16(_g + 16 * ldA, _l + 512); } while (0)
#define STB256(buf, kh, tt) do {                                   \
    const u16* _g = gB + ((long)(tt) << 6) + ((kh) << 5);          \
    u16* _l = &lds[buf][1][kh][wave * 1024];                       \
    glds16(_g, _l); glds16(_g + 16 * ldB, _l + 512); } while (0)
#define BAR256 asm volatile("s_barrier" ::: "memory")
#define LGK0   asm volatile("s_waitcnt lgkmcnt(0)" ::: "memory")

  floatx4 acc[8][4] = {};
  short8 af[4], bq[4];

  // ---- prologue: T0 all 4 halves; T1.{B.kh0, A.kh0, B.kh1}
  STA256(0, 0, 0); STB256(0, 0, 0); STA256(0, 1, 0); STB256(0, 1, 0);
  STB256(1, 0, 1); STA256(1, 0, 1); STB256(1, 1, 1);
  asm volatile("s_waitcnt vmcnt(6)" ::: "memory"); // T0's 8 loads landed
  BAR256;

#define TILE256(kt, buf) do {                                                      \
    const bool s1 = (kt) + 1 < NT, s2 = (kt) + 2 < NT;                             \
    /* ---- ph0: A m0-3 ks0 + B ks0 ---- */                                        \
    _Pragma("unroll") for (int i = 0; i < 4; i++)                                  \
      af[i] = *(const short8*)&lds[buf][0][0][aOff + i * 512];                     \
    _Pragma("unroll") for (int n = 0; n < 4; n++)                                  \
      bq[n] = *(const short8*)&lds[buf][1][0][bOff + n * 512];                     \
    if (s1) STA256((buf) ^ 1, 1, (kt) + 1);                                        \
    BAR256; LGK0;                                                                  \
    __builtin_amdgcn_s_setprio(1);                                                 \
    _Pragma("unroll") for (int i = 0; i < 4; i++)                                  \
      _Pragma("unroll") for (int n = 0; n < 4; n++)                                \
        acc[i][n] = __builtin_amdgcn_mfma_f32_16x16x32_bf16(af[i], bq[n], acc[i][n], 0, 0, 0); \
    __builtin_amdgcn_s_setprio(0);                                                 \
    BAR256;                                                                        \
    /* ---- ph1: A m4-7 ks0 (B reused) ---- */                                     \
    _Pragma("unroll") for (int i = 0; i < 4; i++)                                  \
      af[i] = *(const short8*)&lds[buf][0][0][aOff + (4 + i) * 512];               \
    if (s2) STB256(buf, 0, (kt) + 2);                                              \
    BAR256; LGK0;                                                                  \
    __builtin_amdgcn_s_setprio(1);                                                 \
    _Pragma("unroll") for (int i = 0; i < 4; i++)                                  \
      _Pragma("unroll") for (int n = 0; n < 4; n++)                                \
        acc[4 + i][n] = __builtin_amdgcn_mfma_f32_16x16x32_bf16(af[i], bq[n], acc[4 + i][n], 0, 0, 0); \
    __builtin_amdgcn_s_setprio(0);                                                 \
    BAR256;                                                                        \
    /* ---- ph2: A m0-3 ks1 + B ks1 ---- */                                        \
    _Pragma("unroll") for (int i = 0; i < 4; i++)                                  \
      af[i] = *(const short8*)&lds[buf][0][1][aOff + i * 512];                     \
    _Pragma("unroll") for (int n = 0; n < 4; n++)                                  \
      bq[n] = *(const short8*)&lds[buf][1][1][bOff + n * 512];                     \
    if (s2) STA256(buf, 0, (kt) + 2);                                              \
    BAR256; LGK0;                                                                  \
    __builtin_amdgcn_s_setprio(1);                                                 \
    _Pragma("unroll") for (int i = 0; i < 4; i++)                                  \
      _Pragma("unroll") for (int n = 0; n < 4; n++)                                \
        acc[i][n] = __builtin_amdgcn_mfma_f32_16x16x32_bf16(af[i], bq[n], acc[i][n], 0, 0, 0); \
    __builtin_amdgcn_s_setprio(0);                                                 \
    BAR256;                                                                        \
    /* ---- ph3: A m4-7 ks1 ---- */                                                \
    _Pragma("unroll") for (int i = 0; i < 4; i++)                                  \
      af[i] = *(const short8*)&lds[buf][0][1][aOff + (4 + i) * 512];               \
    if (s2) STB256(buf, 1, (kt) + 2);                                              \
    BAR256; LGK0;                                                                  \
    __builtin_amdgcn_s_setprio(1);                                                 \
    _Pragma("unroll") for (int i = 0; i < 4; i++)                                  \
      _Pragma("unroll") for (int n = 0; n < 4; n++)                                \
        acc[4 + i][n] = __builtin_amdgcn_mfma_f32_16x16x32_bf16(af[i], bq[n], acc[4 + i][n], 0, 0, 0); \
    __builtin_amdgcn_s_setprio(0);                                                 \
    if (s2)      asm volatile("s_waitcnt vmcnt(6)" ::: "memory");                  \
    else if (s1) asm volatile("s_waitcnt vmcnt(0)" ::: "memory");                  \
    BAR256;                                                                        \
  } while (0)

  for (int kt = 0; kt < NT; kt += 2) {
    TILE256(kt, 0);
    TILE256(kt + 1, 1);
  }
#undef TILE256
#undef STA256
#undef STB256
#undef BAR256
#undef LGK0

  const long cBase = (long)bz * strideC;
  if (EPI == 6) {
    float csum[4] = {0.f, 0.f, 0.f, 0.f};
#pragma unroll
    for (int m = 0; m < 8; m++) {
#pragma unroll
      for (int r = 0; r < 4; r++) {
        const int row = tileM + wr * 128 + m * 16 + quad * 4 + r;
        float rs = 0.f;
#pragma unroll
        for (int n = 0; n < 4; n++) {
          const int col = tileN + wc * 64 + n * 16 + l16;
          float v = __expf(acc[m][n][r]);
          ((u16*)Cout)[cBase + (long)row * ldC + col] = f2bf(v);
          rs += v;
          csum[n] += v;
        }
        rs += __shfl_xor(rs, 1, 64);
        rs += __shfl_xor(rs, 2, 64);
        rs += __shfl_xor(rs, 4, 64);
        rs += __shfl_xor(rs, 8, 64);
        if (l16 == 0) atomicAdd(&Zr[row], rs);
      }
    }
#pragma unroll
    for (int n = 0; n < 4; n++) {
      float c = csum[n];
      c += __shfl_xor(c, 16, 64);
      c += __shfl_xor(c, 32, 64);
      if (quad == 0) atomicAdd(&Zc[tileN + wc * 64 + n * 16 + l16], c);
    }
  } else {
#pragma unroll
    for (int m = 0; m < 8; m++) {
#pragma unroll
      for (int r = 0; r < 4; r++) {
        const int row = tileM + wr * 128 + m * 16 + quad * 4 + r;
        float rscale = 1.f;
        if (EPI == 1 || EPI == 4) rscale = 1.f / ev[row];
#pragma unroll
        for (int n = 0; n < 4; n++) {
          const int col = tileN + wc * 64 + n * 16 + l16;
          float v = acc[m][n][r];
          const long cIdx = cBase + (long)row * ldC + col;
          if (EPI == 0) v = __expf(v);
          if (EPI == 1 || EPI == 4) v *= rscale;
          if (EPI == 2) v = gelu_tanh(v + ev[col]);
          if (EPI == 3) v = v + ev[col];
          if (EPI == 5) v = v + bf2f(((u16*)Cout)[cIdx]);
          if (EPI == 4)
            ((float*)Cout)[cIdx] = v;
          else
            ((u16*)Cout)[cIdx] = f2bf(v);
        }
      }
    }
  }
}

extern "C" void kernel_launch(void* const* d_in, const int* in_sizes, int n_in,
                              void* d_out, int out_size, void* d_ws, size_t ws_size,
                              hipStream_t stream) {
  const float* x   = (const float*)d_in[0]; // [B,N,D]
  const float* phi = (const float*)d_in[1]; // [E,S,D]
  const float* w1  = (const float*)d_in[2]; // [E,D,H]
  const float* b1  = (const float*)d_in[3]; // [E,H]
  const float* w2  = (const float*)d_in[4]; // [E,H,D]
  const float* b2  = (const float*)d_in[5]; // [E,D]
  (void)in_sizes; (void)n_in; (void)out_size;
  float* out_f = (float*)d_out;

  char* ws = (char*)d_ws;
  size_t off = 0;
  auto carve = [&](size_t bytes) -> char* {
    char* p = ws + off;
    off += (bytes + 255) & ~(size_t)255;
    return p;
  };

  const size_t SZ_P = (size_t)cN * cES * 2; // 33,554,432 (one P batch)

  // Mode selection by workspace size (lifetime-overlaid layouts):
  //   A2 (>=279.2e6): cache all P + 2 H-chunks (numerics identical to R4)
  //   A4 (>=262.4e6): cache all P + 4 H-chunks (one extra bf16 accum on Yv)
  //   B  (fallback) : R4-exact region-recycled layout with phase-C P recompute
  int nChunk = 2;
  bool cacheP = false;
  if (ws_size >= (size_t)279200000)      { cacheP = true; nChunk = 2; }
  else if (ws_size >= (size_t)262400000) { cacheP = true; nChunk = 4; }
  const int cHCx = cH / nChunk;

  u16 *Pall = nullptr, *PtA = nullptr;                              // mode A
  u16 *Pb = nullptr, *Ptb = nullptr, *P2 = nullptr;                 // mode B
  u16 *Hc, *Xbf, *Xt, *Yv, *Slots, *Yt, *Phibf, *W1t, *W2t;
  float *Z1, *Z2;

  if (cacheP) {
    Pall = (u16*)carve(4 * SZ_P);                         // [phase A -> C]
    const size_t hcBytes = (size_t)cB * cE * cS * cHCx * 2;
    char* RS = carve(SZ_P > hcBytes ? SZ_P : hcBytes);    // Pt (A) / Hc (B)
    PtA = (u16*)RS; Hc = (u16*)RS;
    char* XW2 = carve((size_t)cB * cN * cD * 2);          // Xbf (0->A) / W2t (B)
    Xbf = (u16*)XW2; W2t = (u16*)XW2;
    char* R3r = carve((size_t)cB * cD * cN * 2);          // Xt (0->A) / Yv (B->C)
    Xt = (u16*)R3r; Yv = (u16*)R3r;
    char* R4r = carve((size_t)cB * cES * cD * 2);         // Slots (A->B) / Yt (C)
    Slots = (u16*)R4r; Yt = (u16*)R4r;
    char* PW1 = carve((size_t)cE * cH * cD * 2);          // Phibf (0->A) / W1t (B)
    Phibf = (u16*)PW1; W1t = (u16*)PW1;
  } else {
    char* R1 = carve(2 * SZ_P);                           // multi-use (R4 layout)
    Pb = (u16*)R1; Ptb = (u16*)(R1 + SZ_P); Hc = (u16*)R1; P2 = (u16*)R1;
    Xbf = (u16*)carve((size_t)cB * cN * cD * 2);
    char* R3r = carve((size_t)cB * cD * cN * 2);
    Xt = (u16*)R3r; Yv = (u16*)R3r;
    char* R4r = carve((size_t)cB * cES * cD * 2);
    Slots = (u16*)R4r; Yt = (u16*)R4r;
    Phibf = (u16*)carve((size_t)cES * cD * 2);
    W1t = (u16*)carve((size_t)cE * cH * cD * 2);
    W2t = (u16*)carve((size_t)cE * cD * cH * 2);
  }
  Z1 = (float*)carve((size_t)(cB * cES + cB * cN) * 4);
  Z2 = Z1 + (size_t)cB * cES;

  // ---- phase 0: casts / Xt transpose / zero sums (W transposes deferred in mode A) ----
  convert_kernel<<<2048, 256, 0, stream>>>(x, Xbf, (long)cB * cN * cD);
  convert_kernel<<<1024, 256, 0, stream>>>(phi, Phibf, (long)cES * cD);
  transpose_bf16_kernel<float><<<dim3(cD / 64, cN / 64, cB), 256, 0, stream>>>(
      x, Xt, cN, cD, (long)cN * cD, (long)cD * cN);
  if (!cacheP) {
    transpose_bf16_kernel<float><<<dim3(cH / 64, cD / 64, cE), 256, 0, stream>>>(
        w1, W1t, cD, cH, (long)cD * cH, (long)cH * cD);
    transpose_bf16_kernel<float><<<dim3(cD / 64, cH / 64, cE), 256, 0, stream>>>(
        w2, W2t, cH, cD, (long)cH * cD, (long)cD * cH);
  }
  zero_kernel<<<(cB * (cES + cN)) / 256, 256, 0, stream>>>(Z1, cB * (cES + cN));

  // ---- phase A: per batch, P_b (exp + fused Z1/Z2 sums) -> Pt_b -> Slots_b ----
  for (int b = 0; b < cB; b++) {
    const u16* Xb = Xbf + (long)b * cN * cD;
    u16* Pdst = cacheP ? Pall + (size_t)b * cN * cES : Pb;
    u16* Ptmp = cacheP ? PtA : Ptb;
    gemm256<6><<<dim3(cES / 256, cN / 256, 1), 512, 0, stream>>>(
        Xb, Phibf, Pdst, cN, cES, cD, cD, cD, cES,
        0L, 0L, 1, 0L, Z1, 0, 1,
        Z1 + (long)b * cES, Z2 + (long)b * cN);
    transpose_bf16_kernel<u16><<<dim3(cES / 64, cN / 64, 1), 256, 0, stream>>>(
        Pdst, Ptmp, cN, cES, 0L, 0L);
    gemm_nt<1><<<dim3(cD / 128, cES / 128, 1), 256, 0, stream>>>(
        Ptmp, Xt + (long)b * cD * cN, Slots + (long)b * cES * cD,
        cES, cD, cN, cN, cN, cD,
        0L, 0L, 1, 0L, Z1 + (long)b * cES, 0, 1);
  }

  // mode A: W transposes now (Xbf and Phibf are dead; W2t/W1t overlay them)
  if (cacheP) {
    transpose_bf16_kernel<float><<<dim3(cH / 64, cD / 64, cE), 256, 0, stream>>>(
        w1, W1t, cD, cH, (long)cD * cH, (long)cH * cD);
    transpose_bf16_kernel<float><<<dim3(cD / 64, cH / 64, cE), 256, 0, stream>>>(
        w2, W2t, cH, cD, (long)cH * cD, (long)cD * cH);
  }

  // ---- phase B: MLP in nChunk H-chunks (bz = b*4+e), 256^2 engine ----
  for (int hc = 0; hc < nChunk; hc++) {
    const int h0 = hc * cHCx;
    gemm256<2><<<dim3(cHCx / 256, cS / 256, cB * cE), 512, 0, stream>>>(
        Slots, W1t + (long)h0 * cD, Hc, cS, cHCx, cD, cD, cD, cHCx,
        (long)cS * cD, (long)cH * cD, cE, (long)cS * cHCx, b1 + h0, cH, cE,
        nullptr, nullptr);
    if (hc == 0)
      gemm256<3><<<dim3(cD / 256, cS / 256, cB * cE), 512, 0, stream>>>(
          Hc, W2t + h0, Yv, cS, cD, cHCx, cHCx, cH, cD,
          (long)cS * cHCx, (long)cD * cH, cE, (long)cS * cD, b2, cD, cE,
          nullptr, nullptr);
    else
      gemm256<5><<<dim3(cD / 256, cS / 256, cB * cE), 512, 0, stream>>>(
          Hc, W2t + h0, Yv, cS, cD, cHCx, cHCx, cH, cD,
          (long)cS * cHCx, (long)cD * cH, cE, (long)cS * cD, b2, cD, cE,
          nullptr, nullptr);
  }

  // ---- phase C: Yt (into dead Slots region); combine (P recompute only in mode B) ----
  transpose_bf16_kernel<u16><<<dim3(cD / 64, cES / 64, cB), 256, 0, stream>>>(
      Yv, Yt, cES, cD, (long)cES * cD, (long)cD * cES);
  for (int bp = 0; bp < 2; bp++) {
    const u16* Psrc;
    if (cacheP) {
      Psrc = Pall + (size_t)(bp * 2) * cN * cES;
    } else {
      const u16* Xb = Xbf + (long)(bp * 2) * cN * cD;
      gemm256<0><<<dim3(cES / 256, cN / 256, 2), 512, 0, stream>>>(
          Xb, Phibf, P2, cN, cES, cD, cD, cD, cES,
          (long)cN * cD, 0L, 1, (long)cN * cES, Z1, 0, 1, nullptr, nullptr);
      Psrc = P2;
    }
    gemm_nt<4><<<dim3(cD / 128, cN / 128, 2), 256, 0, stream>>>(
        Psrc, Yt + (long)(bp * 2) * cD * cES, out_f + (long)(bp * 2) * cN * cD,
        cN, cD, cES, cES, cES, cD,
        (long)cN * cES, (long)cD * cES, 2, (long)cN * cD,
        Z2 + (long)(bp * 2) * cN, cN, 2);
  }
}

// Round 7
// 1019.837 us; speedup vs baseline: 1.4009x; 1.0384x over previous
//
#include <hip/hip_runtime.h>
#include <hip/hip_bf16.h>

using u16 = unsigned short;
using short8 = __attribute__((ext_vector_type(8))) short;
using floatx4 = __attribute__((ext_vector_type(4))) float;

#define DEVI static __device__ __forceinline__

constexpr int cB = 4, cN = 4096, cD = 768, cE = 4, cS = 1024, cH = 3072;
constexpr int cES = cE * cS; // 4096

DEVI u16 f2bf(float f) {
  union { float f; unsigned u; } v; v.f = f;
  unsigned r = v.u + 0x7fffu + ((v.u >> 16) & 1u); // RNE
  return (u16)(r >> 16);
}
DEVI float bf2f(u16 b) {
  union { unsigned u; float f; } v; v.u = ((unsigned)b) << 16;
  return v.f;
}
DEVI float gelu_tanh(float x) {
  float z = 1.5957691216057308f * (x + 0.044715f * x * x * x);
  z = fminf(fmaxf(z, -30.f), 30.f);
  float e = __expf(z);
  float t = (e - 1.f) / (e + 1.f);
  return 0.5f * x * (1.f + t);
}

// async global->LDS, 16B per lane; lds dest = wave-uniform base + lane*16
DEVI void glds16(const u16* g, u16* l) {
  __builtin_amdgcn_global_load_lds(
      (const __attribute__((address_space(1))) void*)g,
      (__attribute__((address_space(3))) void*)l, 16, 0, 0);
}

// ---------------- zero fp32 buffer ----------------
__global__ __launch_bounds__(256) void zero_kernel(float* __restrict__ p, int n) {
  int i = blockIdx.x * 256 + threadIdx.x;
  if (i < n) p[i] = 0.f;
}

// ---------------- elementwise convert f32 -> bf16 ----------------
__global__ __launch_bounds__(256) void convert_kernel(const float* __restrict__ in,
                                                      u16* __restrict__ out, long n) {
  long stride = (long)gridDim.x * 256 * 4;
  for (long idx = ((long)blockIdx.x * 256 + threadIdx.x) * 4; idx < n; idx += stride) {
    float4 v = *(const float4*)(in + idx);
    ushort4 o;
    o.x = f2bf(v.x); o.y = f2bf(v.y); o.z = f2bf(v.z); o.w = f2bf(v.w);
    *(ushort4*)(out + idx) = o;
  }
}

// ---------------- batched transpose [R][C] -> [C][R], output bf16 (vectorized) --
template <typename Tin>
__global__ __launch_bounds__(256) void transpose_bf16_kernel(const Tin* __restrict__ in,
                                                             u16* __restrict__ out,
                                                             int R, int C,
                                                             long strideIn, long strideOut) {
  __shared__ u16 tile[64][66];
  const Tin* inb = in + (long)blockIdx.z * strideIn;
  u16* outb = out + (long)blockIdx.z * strideOut;
  const int r0 = blockIdx.y * 64, c0 = blockIdx.x * 64;
  const int tid = threadIdx.x;
#pragma unroll
  for (int i = 0; i < 4; i++) {
    int v = i * 256 + tid;
    int r = v >> 4, c4 = (v & 15) * 4;
    if constexpr (sizeof(Tin) == 4) {
      float4 f = *(const float4*)&inb[(long)(r0 + r) * C + (c0 + c4)];
      tile[r][c4 + 0] = f2bf(f.x); tile[r][c4 + 1] = f2bf(f.y);
      tile[r][c4 + 2] = f2bf(f.z); tile[r][c4 + 3] = f2bf(f.w);
    } else {
      ushort4 u = *(const ushort4*)&inb[(long)(r0 + r) * C + (c0 + c4)];
      tile[r][c4 + 0] = u.x; tile[r][c4 + 1] = u.y;
      tile[r][c4 + 2] = u.z; tile[r][c4 + 3] = u.w;
    }
  }
  __syncthreads();
#pragma unroll
  for (int i = 0; i < 4; i++) {
    int w = i * 256 + tid;
    int orow = w >> 4, oc4 = (w & 15) * 4;
    ushort4 u;
    u.x = tile[oc4 + 0][orow]; u.y = tile[oc4 + 1][orow];
    u.z = tile[oc4 + 2][orow]; u.w = tile[oc4 + 3][orow];
    *(ushort4*)&outb[(long)(c0 + orow) * R + (r0 + oc4)] = u;
  }
}

// ================= 128^2 quad-buffer engine (R1/R6-verified) =================
// Kept for low-fill deep-K shapes (slots EPI1, combine EPI4): distance-3
// prefetch + counted vmcnt hides latency when <1 block/CU of TLP exists.
template <int EPI>
__global__ __launch_bounds__(256, 2) void gemm_nt(const u16* __restrict__ A,
                                                  const u16* __restrict__ Bm,
                                                  void* __restrict__ Cout,
                                                  int M, int Nn, int K,
                                                  long ldA, long ldB, long ldC,
                                                  long strideA, long strideB, int modB,
                                                  long strideC,
                                                  const float* __restrict__ epiVec,
                                                  long epiStride, int epiMod) {
  __shared__ u16 lds[4 * 8192]; // 4 bufs x (A 4096 + B 4096) = 64KB

  const int gx = gridDim.x;
  const int nwg = gx * gridDim.y;
  int flat = blockIdx.y * gx + blockIdx.x;
  if ((nwg & 7) == 0) flat = (flat & 7) * (nwg >> 3) + (flat >> 3);
  const int bxs = flat % gx, bys = flat / gx;

  const int bz = blockIdx.z;
  const u16* Ab = A + (long)bz * strideA;
  const u16* Bb = Bm + (long)(bz % modB) * strideB;
  const float* ev = epiVec + (long)(bz % epiMod) * epiStride;
  const int tileM = bys * 128, tileN = bxs * 128;
  const int tid = threadIdx.x;
  const int wave = tid >> 6, lane = tid & 63;
  const int quad = lane >> 4, l16 = lane & 15;
  const int wm = (wave >> 1) * 64, wn = (wave & 1) * 64;

  const int swzk = (((lane & 3) ^ ((lane >> 3) & 3)) << 3);
  const int r0 = wave * 32 + (lane >> 2);
  const u16* aG0 = Ab + (long)(tileM + r0) * ldA + swzk;
  const u16* aG1 = Ab + (long)(tileM + r0 + 16) * ldA + swzk;
  const u16* bG0 = Bb + (long)(tileN + r0) * ldB + swzk;
  const u16* bG1 = Bb + (long)(tileN + r0 + 16) * ldB + swzk;
  const int ldsW = wave * 1024;

  const int NT = K >> 5;

  auto STAGE = [&](int tt) {
    u16* l = &lds[(tt & 3) * 8192];
    const long ko = (long)tt << 5;
    glds16(aG0 + ko, l + ldsW);
    glds16(aG1 + ko, l + ldsW + 512);
    glds16(bG0 + ko, l + 4096 + ldsW);
    glds16(bG1 + ko, l + 4096 + ldsW + 512);
  };

  floatx4 acc[4][4] = {};
  const int sread = ((quad ^ ((l16 >> 1) & 3)) << 3);

  STAGE(0);
  if (NT > 1) STAGE(1);
  if (NT > 2) STAGE(2);

  for (int t = 0; t < NT; t++) {
    asm volatile("s_barrier" ::: "memory");
    if (t + 3 < NT) STAGE(t + 3);
    const int ahead = NT - 1 - t;
    if (ahead >= 3)      asm volatile("s_waitcnt vmcnt(12)" ::: "memory");
    else if (ahead == 2) asm volatile("s_waitcnt vmcnt(8)" ::: "memory");
    else if (ahead == 1) asm volatile("s_waitcnt vmcnt(4)" ::: "memory");
    else                 asm volatile("s_waitcnt vmcnt(0)" ::: "memory");
    asm volatile("s_barrier" ::: "memory");

    const u16* As = &lds[(t & 3) * 8192];
    const u16* Bs = As + 4096;
    short8 af[4], bq[4];
#pragma unroll
    for (int i = 0; i < 4; i++)
      af[i] = *(const short8*)&As[(wm + i * 16 + l16) * 32 + sread];
#pragma unroll
    for (int j = 0; j < 4; j++)
      bq[j] = *(const short8*)&Bs[(wn + j * 16 + l16) * 32 + sread];
    __builtin_amdgcn_s_setprio(1);
#pragma unroll
    for (int i = 0; i < 4; i++)
#pragma unroll
      for (int j = 0; j < 4; j++)
        acc[i][j] = __builtin_amdgcn_mfma_f32_16x16x32_bf16(af[i], bq[j], acc[i][j], 0, 0, 0);
    __builtin_amdgcn_s_setprio(0);
  }

  const long cBase = (long)bz * strideC;
#pragma unroll
  for (int i = 0; i < 4; i++) {
#pragma unroll
    for (int r = 0; r < 4; r++) {
      const int row = tileM + wm + i * 16 + quad * 4 + r;
      float rscale = 1.f;
      if (EPI == 1 || EPI == 4) rscale = 1.f / ev[row];
#pragma unroll
      for (int j = 0; j < 4; j++) {
        const int col = tileN + wn + j * 16 + l16;
        float v = acc[i][j][r];
        const long cIdx = cBase + (long)row * ldC + col;
        if (EPI == 0) v = __expf(v);
        if (EPI == 1 || EPI == 4) v *= rscale;
        if (EPI == 2) v = gelu_tanh(v + ev[col]);
        if (EPI == 3) v = v + ev[col];
        if (EPI == 5) v = v + bf2f(((u16*)Cout)[cIdx]);
        if (EPI == 4)
          ((float*)Cout)[cIdx] = v;
        else
          ((u16*)Cout)[cIdx] = f2bf(v);
      }
    }
  }
}

// ================= 128^2 m99-structure engine: 32KB LDS, 5 blocks/CU ==========
// Double-buffered, ONE __syncthreads per K-step (its vmcnt/lgkm drain is the
// only wait); latency hidden by cross-block TLP (5 blocks/CU = 20 waves).
// For full-fill grids (>=1024 blocks). EPI as gemm_nt; EPI 6 = exp + fused
// col/row sums (Zc += per-col, Zr += per-row; bases scaled by bz*zcs/zrs).
template <int EPI>
__global__ __launch_bounds__(256, 4) void gemm_s(const u16* __restrict__ A,
                                                 const u16* __restrict__ Bm,
                                                 void* __restrict__ Cout,
                                                 int M, int Nn, int K,
                                                 long ldA, long ldB, long ldC,
                                                 long strideA, long strideB, int modB,
                                                 long strideC,
                                                 const float* __restrict__ epiVec,
                                                 long epiStride, int epiMod,
                                                 float* __restrict__ Zc,
                                                 float* __restrict__ Zr,
                                                 long zcs, long zrs) {
  __shared__ u16 As[2][4096]; // 16KB
  __shared__ u16 Bs[2][4096]; // 16KB

  const int gx = gridDim.x;
  const int nwg = gx * gridDim.y;
  int flat = blockIdx.y * gx + blockIdx.x;
  {
    const int q = nwg >> 3, r = nwg & 7, xc = flat & 7, o = flat >> 3;
    flat = (xc < r ? xc * (q + 1) : r * (q + 1) + (xc - r) * q) + o;
  }
  const int bxs = flat % gx, bys = flat / gx;

  const int bz = blockIdx.z;
  const u16* __restrict__ Ab = A + (long)bz * strideA;
  const u16* __restrict__ Bb = Bm + (long)(bz % modB) * strideB;
  const float* __restrict__ ev = epiVec + (long)(bz % epiMod) * epiStride;
  const int tileM = bys * 128, tileN = bxs * 128;
  const int tid = threadIdx.x;
  const int wave = tid >> 6, lane = tid & 63;
  const int quad = lane >> 4, l16 = lane & 15;
  const int wm = (wave >> 1) * 64, wn = (wave & 1) * 64;

  // staging + T2 swizzle identical to gemm_nt (R1-verified: 0 bank conflicts)
  const int kswz = (((lane & 3) ^ ((lane >> 3) & 3)) << 3);
  const int r0 = wave * 32 + (lane >> 2);
  const u16* aG0 = Ab + (long)(tileM + r0) * ldA + kswz;
  const u16* aG1 = Ab + (long)(tileM + r0 + 16) * ldA + kswz;
  const u16* bG0 = Bb + (long)(tileN + r0) * ldB + kswz;
  const u16* bG1 = Bb + (long)(tileN + r0 + 16) * ldB + kswz;
  const int ldsW = wave * 1024;

  const int NT = K >> 5;
  floatx4 acc[4][4] = {};
  const int sread = ((quad ^ ((l16 >> 1) & 3)) << 3);

  auto STAGE = [&](int tt) {
    const int bf = tt & 1;
    const long ko = (long)tt << 5;
    glds16(aG0 + ko, &As[bf][ldsW]);
    glds16(aG1 + ko, &As[bf][ldsW + 512]);
    glds16(bG0 + ko, &Bs[bf][ldsW]);
    glds16(bG1 + ko, &Bs[bf][ldsW + 512]);
  };

  STAGE(0);
  for (int t = 0; t < NT; t++) {
    __syncthreads();              // drains vmcnt (STAGE(t) landed) + lgkm (t-1 reads done)
    if (t + 1 < NT) STAGE(t + 1); // into the alternate buffer; covered by this step's work
    const u16* Ap = As[t & 1];
    const u16* Bp = Bs[t & 1];
    short8 af[4], bq[4];
#pragma unroll
    for (int i = 0; i < 4; i++)
      af[i] = *(const short8*)&Ap[(wm + i * 16 + l16) * 32 + sread];
#pragma unroll
    for (int j = 0; j < 4; j++)
      bq[j] = *(const short8*)&Bp[(wn + j * 16 + l16) * 32 + sread];
    __builtin_amdgcn_s_setprio(1);
#pragma unroll
    for (int i = 0; i < 4; i++)
#pragma unroll
      for (int j = 0; j < 4; j++)
        acc[i][j] = __builtin_amdgcn_mfma_f32_16x16x32_bf16(af[i], bq[j], acc[i][j], 0, 0, 0);
    __builtin_amdgcn_s_setprio(0);
  }

  const long cBase = (long)bz * strideC;
  if (EPI == 6) {
    float* zc = Zc + (long)bz * zcs;
    float* zr = Zr + (long)bz * zrs;
    float csum[4] = {0.f, 0.f, 0.f, 0.f};
#pragma unroll
    for (int i = 0; i < 4; i++) {
#pragma unroll
      for (int r = 0; r < 4; r++) {
        const int row = tileM + wm + i * 16 + quad * 4 + r;
        float rs = 0.f;
#pragma unroll
        for (int j = 0; j < 4; j++) {
          const int col = tileN + wn + j * 16 + l16;
          float v = __expf(acc[i][j][r]);
          ((u16*)Cout)[cBase + (long)row * ldC + col] = f2bf(v);
          rs += v;
          csum[j] += v;
        }
        rs += __shfl_xor(rs, 1, 64);
        rs += __shfl_xor(rs, 2, 64);
        rs += __shfl_xor(rs, 4, 64);
        rs += __shfl_xor(rs, 8, 64);
        if (l16 == 0) atomicAdd(&zr[row], rs);
      }
    }
#pragma unroll
    for (int j = 0; j < 4; j++) {
      float c = csum[j];
      c += __shfl_xor(c, 16, 64);
      c += __shfl_xor(c, 32, 64);
      if (quad == 0) atomicAdd(&zc[tileN + wn + j * 16 + l16], c);
    }
  } else {
#pragma unroll
    for (int i = 0; i < 4; i++) {
#pragma unroll
      for (int r = 0; r < 4; r++) {
        const int row = tileM + wm + i * 16 + quad * 4 + r;
        float rscale = 1.f;
        if (EPI == 1 || EPI == 4) rscale = 1.f / ev[row];
#pragma unroll
        for (int j = 0; j < 4; j++) {
          const int col = tileN + wn + j * 16 + l16;
          float v = acc[i][j][r];
          const long cIdx = cBase + (long)row * ldC + col;
          if (EPI == 0) v = __expf(v);
          if (EPI == 1 || EPI == 4) v *= rscale;
          if (EPI == 2) v = gelu_tanh(v + ev[col]);
          if (EPI == 3) v = v + ev[col];
          if (EPI == 5) v = v + bf2f(((u16*)Cout)[cIdx]);
          if (EPI == 4)
            ((float*)Cout)[cIdx] = v;
          else
            ((u16*)Cout)[cIdx] = f2bf(v);
        }
      }
    }
  }
}

extern "C" void kernel_launch(void* const* d_in, const int* in_sizes, int n_in,
                              void* d_out, int out_size, void* d_ws, size_t ws_size,
                              hipStream_t stream) {
  const float* x   = (const float*)d_in[0]; // [B,N,D]
  const float* phi = (const float*)d_in[1]; // [E,S,D]
  const float* w1  = (const float*)d_in[2]; // [E,D,H]
  const float* b1  = (const float*)d_in[3]; // [E,H]
  const float* w2  = (const float*)d_in[4]; // [E,H,D]
  const float* b2  = (const float*)d_in[5]; // [E,D]
  (void)in_sizes; (void)n_in; (void)out_size;
  float* out_f = (float*)d_out;

  char* ws = (char*)d_ws;
  size_t off = 0;
  auto carve = [&](size_t bytes) -> char* {
    char* p = ws + off;
    off += (bytes + 255) & ~(size_t)255;
    return p;
  };

  const size_t SZ_P = (size_t)cN * cES * 2; // 33,554,432

  // Mode A3 (>=262.4e6): cache all 4 P batches (no phase-C recompute),
  //   MLP in 3 H-chunks of 1024 (Hc = 33.55MB overlays Pt region; per-chunk
  //   W2 slice transposed into dead Xbf region). Total 262.3 MB.
  // Mode B fallback: R6 layout, 2 chunks, phase-C recompute.
  const bool cacheP = ws_size >= (size_t)262400000;
  const int nChunk = cacheP ? 3 : 2;
  const int cHCx = cH / nChunk; // 1024 (A) / 1536 (B)

  u16 *Pall = nullptr, *PtA = nullptr, *W2c = nullptr;              // mode A
  u16 *Pb = nullptr, *Ptb = nullptr, *P2 = nullptr;                 // mode B
  u16 *Hc, *Xbf, *Xt, *Yv, *Slots, *Yt, *Phibf, *W1t, *W2t = nullptr;
  float *Z1, *Z2;

  if (cacheP) {
    Pall = (u16*)carve(4 * SZ_P);                         // [A -> C]
    char* RS = carve(SZ_P);                               // Pt (A) / Hc (B) 33.55M
    PtA = (u16*)RS; Hc = (u16*)RS;
    char* RX = carve((size_t)cB * cN * cD * 2);           // Xbf (0-A) / W2c (B)
    Xbf = (u16*)RX; W2c = (u16*)RX;
    char* RY = carve((size_t)cB * cD * cN * 2);           // Xt (0-A) / Yv (B-C)
    Xt = (u16*)RY; Yv = (u16*)RY;
    char* RZ = carve((size_t)cB * cES * cD * 2);          // Slots (A-B) / Yt (C)
    Slots = (u16*)RZ; Yt = (u16*)RZ;
    char* RW = carve((size_t)cE * cH * cD * 2);           // Phibf (0-A) / W1t (B)
    Phibf = (u16*)RW; W1t = (u16*)RW;
  } else {
    char* R1 = carve(2 * SZ_P);                           // multi-use
    Pb = (u16*)R1; Ptb = (u16*)(R1 + SZ_P); Hc = (u16*)R1; P2 = (u16*)R1;
    Xbf = (u16*)carve((size_t)cB * cN * cD * 2);
    char* R3r = carve((size_t)cB * cD * cN * 2);
    Xt = (u16*)R3r; Yv = (u16*)R3r;
    char* R4r = carve((size_t)cB * cES * cD * 2);
    Slots = (u16*)R4r; Yt = (u16*)R4r;
    Phibf = (u16*)carve((size_t)cES * cD * 2);
    W1t = (u16*)carve((size_t)cE * cH * cD * 2);
    W2t = (u16*)carve((size_t)cE * cD * cH * 2);
  }
  Z1 = (float*)carve((size_t)(cB * cES + cB * cN) * 4);
  Z2 = Z1 + (size_t)cB * cES;

  // ---- phase 0 ----
  convert_kernel<<<2048, 256, 0, stream>>>(x, Xbf, (long)cB * cN * cD);
  convert_kernel<<<1024, 256, 0, stream>>>(phi, Phibf, (long)cES * cD);
  transpose_bf16_kernel<float><<<dim3(cD / 64, cN / 64, cB), 256, 0, stream>>>(
      x, Xt, cN, cD, (long)cN * cD, (long)cD * cN);
  if (!cacheP) {
    transpose_bf16_kernel<float><<<dim3(cH / 64, cD / 64, cE), 256, 0, stream>>>(
        w1, W1t, cD, cH, (long)cD * cH, (long)cH * cD);
    transpose_bf16_kernel<float><<<dim3(cD / 64, cH / 64, cE), 256, 0, stream>>>(
        w2, W2t, cH, cD, (long)cH * cD, (long)cD * cH);
  }
  zero_kernel<<<(cB * (cES + cN)) / 256, 256, 0, stream>>>(Z1, cB * (cES + cN));

  // ---- phase A ----
  if (cacheP) {
    // all 4 exp GEMMs batched (z=4): P + fused Z1/Z2 sums
    gemm_s<6><<<dim3(cES / 128, cN / 128, cB), 256, 0, stream>>>(
        Xbf, Phibf, Pall, cN, cES, cD, cD, cD, cES,
        (long)cN * cD, 0L, 1, (long)cN * cES, Z1, 0, 1,
        Z1, Z2, (long)cES, (long)cN);
    for (int b = 0; b < cB; b++) {
      transpose_bf16_kernel<u16><<<dim3(cES / 64, cN / 64, 1), 256, 0, stream>>>(
          Pall + (size_t)b * cN * cES, PtA, cN, cES, 0L, 0L);
      gemm_nt<1><<<dim3(cD / 128, cES / 128, 1), 256, 0, stream>>>(
          PtA, Xt + (long)b * cD * cN, Slots + (long)b * cES * cD,
          cES, cD, cN, cN, cN, cD,
          0L, 0L, 1, 0L, Z1 + (long)b * cES, 0, 1);
    }
    // W1t now (Phibf dead after exp; W1t overlays it)
    transpose_bf16_kernel<float><<<dim3(cH / 64, cD / 64, cE), 256, 0, stream>>>(
        w1, W1t, cD, cH, (long)cD * cH, (long)cH * cD);
  } else {
    for (int b = 0; b < cB; b++) {
      const u16* Xb = Xbf + (long)b * cN * cD;
      gemm_s<6><<<dim3(cES / 128, cN / 128, 1), 256, 0, stream>>>(
          Xb, Phibf, Pb, cN, cES, cD, cD, cD, cES,
          0L, 0L, 1, 0L, Z1, 0, 1,
          Z1 + (long)b * cES, Z2 + (long)b * cN, 0L, 0L);
      transpose_bf16_kernel<u16><<<dim3(cES / 64, cN / 64, 1), 256, 0, stream>>>(
          Pb, Ptb, cN, cES, 0L, 0L);
      gemm_nt<1><<<dim3(cD / 128, cES / 128, 1), 256, 0, stream>>>(
          Ptb, Xt + (long)b * cD * cN, Slots + (long)b * cES * cD,
          cES, cD, cN, cN, cN, cD,
          0L, 0L, 1, 0L, Z1 + (long)b * cES, 0, 1);
    }
  }

  // ---- phase B: MLP in nChunk H-chunks (bz = b*4+e) ----
  for (int hc = 0; hc < nChunk; hc++) {
    const int h0 = hc * cHCx;
    const u16* W2base;
    long ldB2, strideB2;
    if (cacheP) {
      // per-chunk W2 slice transpose into dead Xbf region: [e][d][cHCx]
      transpose_bf16_kernel<float><<<dim3(cD / 64, cHCx / 64, cE), 256, 0, stream>>>(
          w2 + (long)h0 * cD, W2c, cHCx, cD, (long)cH * cD, (long)cD * cHCx);
      W2base = W2c; ldB2 = cHCx; strideB2 = (long)cD * cHCx;
    } else {
      W2base = W2t + h0; ldB2 = cH; strideB2 = (long)cD * cH;
    }
    gemm_s<2><<<dim3(cHCx / 128, cS / 128, cB * cE), 256, 0, stream>>>(
        Slots, W1t + (long)h0 * cD, Hc, cS, cHCx, cD, cD, cD, cHCx,
        (long)cS * cD, (long)cH * cD, cE, (long)cS * cHCx, b1 + h0, cH, cE,
        nullptr, nullptr, 0L, 0L);
    if (hc == 0)
      gemm_s<3><<<dim3(cD / 128, cS / 128, cB * cE), 256, 0, stream>>>(
          Hc, W2base, Yv, cS, cD, cHCx, cHCx, ldB2, cD,
          (long)cS * cHCx, strideB2, cE, (long)cS * cD, b2, cD, cE,
          nullptr, nullptr, 0L, 0L);
    else
      gemm_s<5><<<dim3(cD / 128, cS / 128, cB * cE), 256, 0, stream>>>(
          Hc, W2base, Yv, cS, cD, cHCx, cHCx, ldB2, cD,
          (long)cS * cHCx, strideB2, cE, (long)cS * cD, b2, cD, cE,
          nullptr, nullptr, 0L, 0L);
  }

  // ---- phase C ----
  transpose_bf16_kernel<u16><<<dim3(cD / 64, cES / 64, cB), 256, 0, stream>>>(
      Yv, Yt, cES, cD, (long)cES * cD, (long)cD * cES);
  for (int bp = 0; bp < 2; bp++) {
    const u16* Psrc;
    if (cacheP) {
      Psrc = Pall + (size_t)(bp * 2) * cN * cES;
    } else {
      const u16* Xb = Xbf + (long)(bp * 2) * cN * cD;
      gemm_s<0><<<dim3(cES / 128, cN / 128, 2), 256, 0, stream>>>(
          Xb, Phibf, P2, cN, cES, cD, cD, cD, cES,
          (long)cN * cD, 0L, 1, (long)cN * cES, Z1, 0, 1,
          nullptr, nullptr, 0L, 0L);
      Psrc = P2;
    }
    gemm_nt<4><<<dim3(cD / 128, cN / 128, 2), 256, 0, stream>>>(
        Psrc, Yt + (long)(bp * 2) * cD * cES, out_f + (long)(bp * 2) * cN * cD,
        cN, cD, cES, cES, cES, cD,
        (long)cN * cES, (long)cD * cES, 2, (long)cN * cD,
        Z2 + (long)(bp * 2) * cN, cN, 2);
  }
}